// Round 12
// baseline (208.751 us; speedup 1.0000x reference)
//
#include <hip/hip_runtime.h>
#include <math.h>

#define TT 4096
#define BB 4
#define DM 256
#define NSEG_B 144  // per batch: 128-row q-tiles x 512-key segments: sum ceil((qt+1)/4), qt<32

typedef __attribute__((ext_vector_type(8))) short short8;
typedef __attribute__((ext_vector_type(4))) short short4v;
typedef __attribute__((ext_vector_type(4))) float f32x4;

#define MFMA16(a, b, c) __builtin_amdgcn_mfma_f32_16x16x32_bf16(a, b, c, 0, 0, 0)

// async global->LDS DMA, 16B/lane; LDS dest = wave-uniform base + lane*16
#define GL2LDS(gp, lp) __builtin_amdgcn_global_load_lds( \
    (const __attribute__((address_space(1))) unsigned int*)(gp), \
    (__attribute__((address_space(3))) unsigned int*)(lp), 16, 0, 0)

// fp32 -> bf16 round-to-nearest-even (finite inputs)
__device__ __forceinline__ short f2b(float f) {
    union { float f; unsigned u; } v; v.f = f;
    unsigned r = v.u + 0x7FFFu + ((v.u >> 16) & 1u);
    return (short)(r >> 16);
}
// bf16 bits -> fp32
__device__ __forceinline__ float b2f(short h) {
    union { unsigned u; float f; } v;
    v.u = ((unsigned)(unsigned short)h) << 16;
    return v.f;
}

// ---------------------------------------------------------------------------
// Fused tile-transpose + cast: W fp32 [256][N] -> Wt bf16 [N][256]
// ---------------------------------------------------------------------------
__global__ __launch_bounds__(256) void transpose_cast2(
    const float* __restrict__ W1, short* __restrict__ Wt1,
    const float* __restrict__ W2, short* __restrict__ Wt2)
{
    __shared__ float T[64 * 68];
    const int tid = threadIdx.x;
    const int by = blockIdx.y;
    const float* W; short* Wt; int N, n0;
    if (by < 12) { W = W1; Wt = Wt1; N = 768; n0 = by * 64; }
    else         { W = W2; Wt = Wt2; N = 256; n0 = (by - 12) * 64; }
    const int k0 = blockIdx.x * 64;
#pragma unroll
    for (int it = 0; it < 4; ++it) {
        int idx = tid + it * 256;
        int r = idx >> 4, c4 = idx & 15;
        *(float4*)&T[r * 68 + c4 * 4] =
            *(const float4*)&W[(size_t)(k0 + r) * N + n0 + c4 * 4];
    }
    __syncthreads();
#pragma unroll
    for (int it = 0; it < 4; ++it) {
        int idx = tid + it * 256;
        int n = idx >> 4, c4 = idx & 15;
        short4v t;
#pragma unroll
        for (int j = 0; j < 4; ++j) t[j] = f2b(T[(c4 * 4 + j) * 68 + n]);
        *(short4v*)&Wt[(size_t)(n0 + n) * 256 + k0 + c4 * 4] = t;
    }
}

// ---------------------------------------------------------------------------
// QKV GEMM v3: qkv = x @ Wqkv + b. BM=64, n-super 384 (grid (256,2)); A
// staged once per block; Bs staged (r10: direct-B regresses). NEW (r12):
// q/k tiles ALSO routed through the Ts transpose -> fully-coalesced 16B
// row-major stores (was: 16 scalar 2B scattered stores/thread — the
// suspected chunk of the opaque non-flash ~115us). Sync count unchanged
// (2/tile: Bs-stage sync + Ts sync).
// ---------------------------------------------------------------------------
__global__ __launch_bounds__(256) void qkv_gemm(
    const float* __restrict__ x, const short* __restrict__ Bt,
    const float* __restrict__ bias, short* __restrict__ qkvb,
    short* __restrict__ VtG)
{
    __shared__ short As[16384];
    __shared__ short Bs[16384];
    __shared__ short Ts[64 * 72];

    const int tid = threadIdx.x;
    const int w = tid >> 6, lane = tid & 63;
    const int l15 = lane & 15, quad = lane >> 4;
    const int m0 = blockIdx.x * 64;
    const int nsup = blockIdx.y * 384;

#pragma unroll
    for (int it = 0; it < 8; ++it) {
        int idx = tid + it * 256;
        int row = ((idx >> 9) << 4) + (idx & 15);
        int col = ((idx >> 6) & 7) * 32 + ((idx >> 4) & 3) * 8;
        const float* src = &x[(size_t)(m0 + row) * 256 + col];
        float4 u = *(const float4*)src, u2 = *(const float4*)(src + 4);
        short8 t;
        t[0] = f2b(u.x);  t[1] = f2b(u.y);  t[2] = f2b(u.z);  t[3] = f2b(u.w);
        t[4] = f2b(u2.x); t[5] = f2b(u2.y); t[6] = f2b(u2.z); t[7] = f2b(u2.w);
        *(short8*)&As[idx * 8] = t;
    }

    for (int t6 = 0; t6 < 6; ++t6) {
        const int n0 = nsup + t6 * 64;
#pragma unroll
        for (int it = 0; it < 8; ++it) {
            int idx = tid + it * 256;
            int n = ((idx >> 9) << 4) + (idx & 15);
            int col = ((idx >> 6) & 7) * 32 + ((idx >> 4) & 3) * 8;
            *(short8*)&Bs[idx * 8] = *(const short8*)&Bt[(size_t)(n0 + n) * 256 + col];
        }
        __syncthreads();

        f32x4 acc[4];
#pragma unroll
        for (int t = 0; t < 4; ++t) acc[t] = (f32x4){0.f, 0.f, 0.f, 0.f};
#pragma unroll
        for (int k0 = 0; k0 < 8; ++k0) {
            short8 a = *(const short8*)&As[((w * 8 + k0) * 64 + lane) * 8];
#pragma unroll
            for (int nt = 0; nt < 4; ++nt) {
                short8 bb = *(const short8*)&Bs[((nt * 8 + k0) * 64 + lane) * 8];
                acc[nt] = MFMA16(a, bb, acc[nt]);
            }
        }

        // write acc+bias to Ts [n][row] (prev tile's Ts readers finished
        // before this tile's Bs-stage sync)
#pragma unroll
        for (int nt = 0; nt < 4; ++nt) {
            int n = n0 + nt * 16 + l15;
            float bv = bias[n];
#pragma unroll
            for (int r = 0; r < 4; ++r)
                Ts[(nt * 16 + l15) * 72 + w * 16 + quad * 4 + r]
                    = f2b(acc[nt][r] + bv);
        }
        __syncthreads();   // Ts ready

        if (n0 < 512) {
            // coalesced row-major store: thread = (row, 16-col group)
            const int row = tid >> 2;
            const int c   = tid & 3;
            short8 s0, s1;
#pragma unroll
            for (int j = 0; j < 8; ++j) {
                s0[j] = Ts[(c * 16 + j) * 72 + row];
                s1[j] = Ts[(c * 16 + 8 + j) * 72 + row];
            }
            short* dst = &qkvb[(size_t)(m0 + row) * 768 + n0 + c * 16];
            *(short8*)dst = s0;
            *(short8*)(dst + 8) = s1;
        } else {
            const int d  = tid >> 2;
            const int c  = tid & 3;
            short8 v0 = *(const short8*)&Ts[d * 72 + c * 16];
            short8 v1 = *(const short8*)&Ts[d * 72 + c * 16 + 8];
            const int bg = m0 >> 12, key0 = (m0 & 4095) + c * 16;
            short* dst = &VtG[((size_t)bg * 256 + (n0 - 512) + d) * 4096 + key0];
            *(short8*)dst = v0;
            *(short8*)(dst + 8) = v1;
        }
    }
}

// ---------------------------------------------------------------------------
// Split-K flash v10 (FROZEN, r11: 92.4us best-measured): BM=128, 4 waves,
// 2 rowsets/wave; grid 576 (512-key segments); 40KB LDS; V single-buffered;
// 3 barriers/unit: A=__syncthreads, B=vmcnt(4)+s_barrier, C=vmcnt(2|0)+
// s_barrier; bf16 Opart. r7/r8/r10 falsified deeper prefetch / fewer
// barriers / no-staging — this cadence is the optimum for this structure.
// ---------------------------------------------------------------------------
__global__ __launch_bounds__(256, 2) void flash_mfma(
    const short* __restrict__ qkv,   // (B*T, 768) bf16 q|k|v
    const short* __restrict__ VtG,   // (B, 256, 4096) bf16 V^T
    short* __restrict__ Opart,       // (576, 128, 256) bf16
    float* __restrict__ L)           // (576, 128) fp32
{
    __shared__ short Ks[2][4096];   // 16 keys x 256 dims, chunked (8KB each)
    __shared__ short Vs[8192];      // 256 dims x 32 keys, chunked (16KB)
    __shared__ short Ps[4096];      // 128 q x 32 keys, A-layout chunked (8KB)

    const int tid = threadIdx.x;
    const int w = tid >> 6, lane = tid & 63;
    const int l15 = lane & 15, quad = lane >> 4;

    // heavy-first, batch-interleaved decode (128-row tiles, 512-key segments)
    const int b = blockIdx.x & 3;
    const int e = (NSEG_B - 1) - (blockIdx.x >> 2);
    const int lid = b * NSEG_B + e;
    int g = 0;
    while (g < 7 && e >= 2 * (g + 1) * (g + 2)) ++g;
    int off = e - 2 * g * (g + 1);
    int qt = 4 * g + off / (g + 1);
    int s  = off - (off / (g + 1)) * (g + 1);
    const int kp_lo = s * 16;                  // 32-key pairs
    const int kp_hi = min(kp_lo + 16, 4 * (qt + 1));
    const int npairs = kp_hi - kp_lo;

    const size_t base = (size_t)b * TT * 768;
    const int row0 = qt * 128;

    // ---- Q frags for both rowsets -> regs (A-layout: row=l15, k=quad*8+j) ----
    short8 aq[2][8];
#pragma unroll
    for (int rs = 0; rs < 2; ++rs) {
        const short* qrow = &qkv[base + (size_t)(row0 + rs * 64 + w * 16 + l15) * 768 + quad * 8];
#pragma unroll
        for (int k0 = 0; k0 < 8; ++k0)
            aq[rs][k0] = *(const short8*)&qrow[k0 * 32];
    }

    // ---- prologue: DMA K chunk 0 -> Ks[0] only ----
#pragma unroll
    for (int it = 0; it < 2; ++it) {
        int idx = tid + it * 256;
        int row = idx & 15;
        int col = ((idx >> 6) & 7) * 32 + ((idx >> 4) & 3) * 8;
        GL2LDS(&qkv[base + (size_t)(kp_lo * 32 + row) * 768 + 256 + col], &Ks[0][idx * 8]);
    }

    f32x4 o[2][16];
#pragma unroll
    for (int rs = 0; rs < 2; ++rs)
#pragma unroll
        for (int c = 0; c < 16; ++c) o[rs][c] = (f32x4){0.f, 0.f, 0.f, 0.f};
    float l_acc[2][4] = {{0.f, 0.f, 0.f, 0.f}, {0.f, 0.f, 0.f, 0.f}};

    for (int u = 0; u < npairs; ++u) {
        const int j0 = (kp_lo + u) * 32;

        // ===== barrier A: K(2u) ready; all waves past PV(u-1) -> Vs free =====
        __syncthreads();

        // issue K chunk 2u+1 -> Ks[1]  (2 instr/wave, FIRST in queue)
#pragma unroll
        for (int it = 0; it < 2; ++it) {
            int idx = tid + it * 256;
            int row = idx & 15;
            int col = ((idx >> 6) & 7) * 32 + ((idx >> 4) & 3) * 8;
            GL2LDS(&qkv[base + (size_t)(j0 + 16 + row) * 768 + 256 + col], &Ks[1][idx * 8]);
        }
        __builtin_amdgcn_sched_barrier(0);   // pin order: K before V
        // issue V pair u -> Vs (4 instr/wave, consumed at PV(u) this unit)
#pragma unroll
        for (int it = 0; it < 4; ++it) {
            int idx = tid + it * 256;
            int d  = ((idx >> 6) << 4) + (idx & 15);
            int kc = ((idx >> 4) & 3) * 8;
            GL2LDS(&VtG[((size_t)b * 256 + d) * 4096 + j0 + kc], &Vs[idx * 8]);
        }
        __builtin_amdgcn_sched_barrier(0);

        // ---- even phase: S = Q K^T on keys [j0, j0+16), both rowsets ----
        {
            f32x4 s4[2];
            s4[0] = (f32x4){0.f, 0.f, 0.f, 0.f};
            s4[1] = (f32x4){0.f, 0.f, 0.f, 0.f};
#pragma unroll
            for (int k0 = 0; k0 < 8; ++k0) {
                short8 bb = *(const short8*)&Ks[0][(k0 * 64 + lane) * 8];
                s4[0] = MFMA16(aq[0][k0], bb, s4[0]);
                s4[1] = MFMA16(aq[1][k0], bb, s4[1]);
            }
#pragma unroll
            for (int rs = 0; rs < 2; ++rs)
#pragma unroll
                for (int r = 0; r < 4; ++r) {
                    const int rg = row0 + rs * 64 + w * 16 + quad * 4 + r;
                    int jg = j0 + l15;
                    float xx = s4[rs][r] * 0.0625f;   // 1/sqrt(256)
                    if (jg > rg) xx = -INFINITY;
                    float pv = __expf(fminf(xx, 30.f));
                    l_acc[rs][r] += pv;
                    Ps[((rs * 4 + w) * 64 + (0 * 2 + (l15 >> 3)) * 16 + quad * 4 + r) * 8
                       + (l15 & 7)] = f2b(pv);
                }
        }

        // ===== barrier B: K(2u+1) done (oldest 2 of [K2,V4]); V(u) in flight
        asm volatile("s_waitcnt vmcnt(4)" ::: "memory");
        __builtin_amdgcn_s_barrier();
        __builtin_amdgcn_sched_barrier(0);

        // issue K chunk 2u+2 -> Ks[0] (next pair's even chunk)
        if (u + 1 < npairs) {
#pragma unroll
            for (int it = 0; it < 2; ++it) {
                int idx = tid + it * 256;
                int row = idx & 15;
                int col = ((idx >> 6) & 7) * 32 + ((idx >> 4) & 3) * 8;
                GL2LDS(&qkv[base + (size_t)(j0 + 32 + row) * 768 + 256 + col], &Ks[0][idx * 8]);
            }
        }
        __builtin_amdgcn_sched_barrier(0);

        // ---- odd phase: S = Q K^T on keys [j0+16, j0+32), both rowsets ----
        {
            f32x4 s4[2];
            s4[0] = (f32x4){0.f, 0.f, 0.f, 0.f};
            s4[1] = (f32x4){0.f, 0.f, 0.f, 0.f};
#pragma unroll
            for (int k0 = 0; k0 < 8; ++k0) {
                short8 bb = *(const short8*)&Ks[1][(k0 * 64 + lane) * 8];
                s4[0] = MFMA16(aq[0][k0], bb, s4[0]);
                s4[1] = MFMA16(aq[1][k0], bb, s4[1]);
            }
#pragma unroll
            for (int rs = 0; rs < 2; ++rs)
#pragma unroll
                for (int r = 0; r < 4; ++r) {
                    const int rg = row0 + rs * 64 + w * 16 + quad * 4 + r;
                    int jg = j0 + 16 + l15;
                    float xx = s4[rs][r] * 0.0625f;
                    if (jg > rg) xx = -INFINITY;
                    float pv = __expf(fminf(xx, 30.f));
                    l_acc[rs][r] += pv;
                    Ps[((rs * 4 + w) * 64 + (1 * 2 + (l15 >> 3)) * 16 + quad * 4 + r) * 8
                       + (l15 & 7)] = f2b(pv);
                }
        }

        // ===== barrier C: V(u) landed wave-wide; K(2u+2) stays in flight =====
        if (u + 1 < npairs) {
            asm volatile("s_waitcnt vmcnt(2)" ::: "memory");
        } else {
            asm volatile("s_waitcnt vmcnt(0)" ::: "memory");
        }
        __builtin_amdgcn_s_barrier();
        __builtin_amdgcn_sched_barrier(0);

        // ---- O += P V over the full 32-key pair; V-frag feeds both rowsets --
        {
            short8 a0 = *(const short8*)&Ps[((0 * 4 + w) * 64 + lane) * 8];
            short8 a1 = *(const short8*)&Ps[((1 * 4 + w) * 64 + lane) * 8];
#pragma unroll
            for (int ct = 0; ct < 16; ++ct) {
                short8 bb = *(const short8*)&Vs[(ct * 64 + lane) * 8];
                o[0][ct] = MFMA16(a0, bb, o[0][ct]);
                o[1][ct] = MFMA16(a1, bb, o[1][ct]);
            }
        }
    }

    // ---- epilogue: reduce l across col-lanes; store bf16 partials ----
#pragma unroll
    for (int rs = 0; rs < 2; ++rs)
#pragma unroll
        for (int r = 0; r < 4; ++r) {
            float l = l_acc[rs][r];
            l += __shfl_xor(l, 1); l += __shfl_xor(l, 2);
            l += __shfl_xor(l, 4); l += __shfl_xor(l, 8);
            if (l15 == 0)
                L[(size_t)lid * 128 + rs * 64 + w * 16 + quad * 4 + r] = l;
        }
    const size_t ob = (size_t)lid * (128 * 256);
#pragma unroll
    for (int rs = 0; rs < 2; ++rs)
#pragma unroll
        for (int r = 0; r < 4; ++r) {
            int lr = rs * 64 + w * 16 + quad * 4 + r;
#pragma unroll
            for (int c = 0; c < 16; ++c)
                Opart[ob + (size_t)lr * 256 + c * 16 + l15] = f2b(o[rs][c][r]);
        }
}

// ---------------------------------------------------------------------------
// Fused merge + proj GEMM v4: out = ((sum O_s)/l) @ Wproj + b.
// 32-token tiles (grid 512), staged Bs, bf16 Opart. NEW (r12): out written
// via LDS transpose (Bs reused as fp32 staging after MFMA) -> coalesced
// float4 stores (was: 8 scalar dword stores/thread/tile). +1 sync/tile.
// ---------------------------------------------------------------------------
__global__ __launch_bounds__(256) void proj_gemm(
    const short* __restrict__ Opart, const float* __restrict__ L,
    const short* __restrict__ Bt, const float* __restrict__ bias,
    float* __restrict__ out)
{
    __shared__ short As[8192];     // 32 x 256 bf16
    __shared__ short Bs[16384];    // 64 x 256 bf16 / reused as fp32 out-stage
    __shared__ float Linv[32];

    const int tid = threadIdx.x;
    const int w = tid >> 6, lane = tid & 63;
    const int l15 = lane & 15, quad = lane >> 4;
    const int t = blockIdx.x;              // 0..511 (32-token tiles)
    const int b = t >> 7, q32 = t & 127;
    const int qt = q32 >> 2;               // 128-row flash tile 0..31
    const int ro = (q32 & 3) * 32;         // row offset inside the flash tile
    const int gg = qt >> 2, rr = qt & 3;
    const int sbase = b * NSEG_B + 2 * gg * (gg + 1) + rr * (gg + 1);
    const int nseg = gg + 1;               // 1..8
    const int m0 = t * 32;

    if (tid < 32) {
        float l = 0.f;
#pragma unroll
        for (int s2 = 0; s2 < 8; ++s2)
            if (s2 < nseg) l += L[(size_t)(sbase + s2) * 128 + ro + tid];
        Linv[tid] = 1.f / l;
    }
    __syncthreads();

    // ---- stage A = normalized merged bf16 partials -> bf16 ----
#pragma unroll
    for (int it = 0; it < 4; ++it) {
        int idx = tid + it * 256;                       // 0..1023
        int row = ((idx >> 9) << 4) + (idx & 15);       // 0..31
        int col = ((idx >> 6) & 7) * 32 + ((idx >> 4) & 3) * 8;
        float a8[8] = {0.f, 0.f, 0.f, 0.f, 0.f, 0.f, 0.f, 0.f};
#pragma unroll
        for (int s2 = 0; s2 < 8; ++s2) {
            if (s2 < nseg) {
                short8 hv = *(const short8*)&Opart[(size_t)(sbase + s2) * 32768
                                                   + (size_t)(ro + row) * 256 + col];
#pragma unroll
                for (int j = 0; j < 8; ++j) a8[j] += b2f(hv[j]);
            }
        }
        float inv = Linv[row];
        short8 t8;
#pragma unroll
        for (int j = 0; j < 8; ++j) t8[j] = f2b(a8[j] * inv);
        *(short8*)&As[idx * 8] = t8;
    }

    for (int t2 = 0; t2 < 4; ++t2) {
        const int n0 = t2 * 64;
#pragma unroll
        for (int it = 0; it < 8; ++it) {
            int idx = tid + it * 256;                   // 0..2047
            int n = ((idx >> 9) << 4) + (idx & 15);     // 0..63
            int col = ((idx >> 6) & 7) * 32 + ((idx >> 4) & 3) * 8;
            *(short8*)&Bs[idx * 8] = *(const short8*)&Bt[(size_t)(n0 + n) * 256 + col];
        }
        __syncthreads();

        f32x4 acc[2];
        acc[0] = (f32x4){0.f, 0.f, 0.f, 0.f};
        acc[1] = (f32x4){0.f, 0.f, 0.f, 0.f};
#pragma unroll
        for (int k0 = 0; k0 < 8; ++k0) {
            short8 a = *(const short8*)&As[(((w & 1) * 8 + k0) * 64 + lane) * 8];
#pragma unroll
            for (int nt = 0; nt < 2; ++nt) {
                int n16 = (w >> 1) * 2 + nt;
                short8 bb = *(const short8*)&Bs[((n16 * 8 + k0) * 64 + lane) * 8];
                acc[nt] = MFMA16(a, bb, acc[nt]);
            }
        }
        __syncthreads();   // all waves done reading Bs -> reuse as fp32 stage

        // stage acc+bias into BsF[col][row] (64 x 33 fp32, pad kills conflicts)
        {
            float* BsF = (float*)Bs;
#pragma unroll
            for (int nt = 0; nt < 2; ++nt) {
                int colt = ((w >> 1) * 2 + nt) * 16 + l15;   // 0..63
                float bv = bias[n0 + colt];
#pragma unroll
                for (int r = 0; r < 4; ++r)
                    BsF[colt * 33 + (w & 1) * 16 + quad * 4 + r] = acc[nt][r] + bv;
            }
        }
        __syncthreads();   // stage ready

        // coalesced float4 stores: thread = (row, 8-col group)
        {
            const float* BsF = (const float*)Bs;
            const int row = tid >> 3;          // 0..31
            const int cg  = tid & 7;           // 0..7
            float4 f0, f1;
            f0.x = BsF[(cg * 8 + 0) * 33 + row];
            f0.y = BsF[(cg * 8 + 1) * 33 + row];
            f0.z = BsF[(cg * 8 + 2) * 33 + row];
            f0.w = BsF[(cg * 8 + 3) * 33 + row];
            f1.x = BsF[(cg * 8 + 4) * 33 + row];
            f1.y = BsF[(cg * 8 + 5) * 33 + row];
            f1.z = BsF[(cg * 8 + 6) * 33 + row];
            f1.w = BsF[(cg * 8 + 7) * 33 + row];
            float* dst = &out[(size_t)(m0 + row) * 256 + n0 + cg * 8];
            *(float4*)dst = f0;
            *(float4*)(dst + 4) = f1;
        }
        __syncthreads();   // stage reads done -> next tile may restage Bs
    }
}

// ---------------------------------------------------------------------------
extern "C" void kernel_launch(void* const* d_in, const int* in_sizes, int n_in,
                              void* d_out, int out_size, void* d_ws, size_t ws_size,
                              hipStream_t stream)
{
    const float* x     = (const float*)d_in[0];   // (4,4096,256)
    const float* Wqkv  = (const float*)d_in[1];   // (256,768)
    const float* bqkv  = (const float*)d_in[2];   // (768,)
    const float* Wproj = (const float*)d_in[3];   // (256,256)
    const float* bproj = (const float*)d_in[4];   // (256,)
    float* out = (float*)d_out;                   // (4,4096,256) fp32

    const size_t M = (size_t)BB * TT;             // 16384
    short* qkv_b = (short*)d_ws;                  // M x 768 bf16      (25.2 MB)
    short* Wt1   = qkv_b + M * 768;               // 768 x 256 bf16
    short* Wt2   = Wt1 + (size_t)768 * 256;       // 256 x 256 bf16
    short* VtG   = Wt2 + (size_t)256 * 256;       // 4 x 256 x 4096 bf16 (8.4 MB)
    short* Opart = VtG + (size_t)BB * 256 * 4096; // 576x128x256 bf16 (37.7 MB)
    float* L     = (float*)(Opart + (size_t)BB * NSEG_B * 128 * 256); // 576x128 f32
    // total workspace ~72 MB

    transpose_cast2<<<dim3(4, 16), dim3(256), 0, stream>>>(Wqkv, Wt1, Wproj, Wt2);
    qkv_gemm<<<dim3(256, 2), dim3(256), 0, stream>>>(x, Wt1, bqkv, qkv_b, VtG);
    flash_mfma<<<dim3(BB * NSEG_B), dim3(256), 0, stream>>>(qkv_b, VtG, Opart, L);
    proj_gemm<<<dim3(512), dim3(256), 0, stream>>>(Opart, L, Wt2, bproj, out);
}

// Round 13
// 193.372 us; speedup vs baseline: 1.0795x; 1.0795x over previous
//
#include <hip/hip_runtime.h>
#include <math.h>

#define TT 4096
#define BB 4
#define DM 256
#define NSLOT 320   // stream-K partial slots: 256 blocks + 63 tile-crossings, sid = k + T_glob < 320

typedef __attribute__((ext_vector_type(8))) short short8;
typedef __attribute__((ext_vector_type(4))) short short4v;
typedef __attribute__((ext_vector_type(4))) float f32x4;

#define MFMA16(a, b, c) __builtin_amdgcn_mfma_f32_16x16x32_bf16(a, b, c, 0, 0, 0)

// async global->LDS DMA, 16B/lane; LDS dest = wave-uniform base + lane*16
#define GL2LDS(gp, lp) __builtin_amdgcn_global_load_lds( \
    (const __attribute__((address_space(1))) unsigned int*)(gp), \
    (__attribute__((address_space(3))) unsigned int*)(lp), 16, 0, 0)

// fp32 -> bf16 round-to-nearest-even (finite inputs)
__device__ __forceinline__ short f2b(float f) {
    union { float f; unsigned u; } v; v.f = f;
    unsigned r = v.u + 0x7FFFu + ((v.u >> 16) & 1u);
    return (short)(r >> 16);
}
// bf16 bits -> fp32
__device__ __forceinline__ float b2f(short h) {
    union { unsigned u; float f; } v;
    v.u = ((unsigned)(unsigned short)h) << 16;
    return v.f;
}

// ---------------------------------------------------------------------------
// Fused tile-transpose + cast: W fp32 [256][N] -> Wt bf16 [N][256]
// ---------------------------------------------------------------------------
__global__ __launch_bounds__(256) void transpose_cast2(
    const float* __restrict__ W1, short* __restrict__ Wt1,
    const float* __restrict__ W2, short* __restrict__ Wt2)
{
    __shared__ float T[64 * 68];
    const int tid = threadIdx.x;
    const int by = blockIdx.y;
    const float* W; short* Wt; int N, n0;
    if (by < 12) { W = W1; Wt = Wt1; N = 768; n0 = by * 64; }
    else         { W = W2; Wt = Wt2; N = 256; n0 = (by - 12) * 64; }
    const int k0 = blockIdx.x * 64;
#pragma unroll
    for (int it = 0; it < 4; ++it) {
        int idx = tid + it * 256;
        int r = idx >> 4, c4 = idx & 15;
        *(float4*)&T[r * 68 + c4 * 4] =
            *(const float4*)&W[(size_t)(k0 + r) * N + n0 + c4 * 4];
    }
    __syncthreads();
#pragma unroll
    for (int it = 0; it < 4; ++it) {
        int idx = tid + it * 256;
        int n = idx >> 4, c4 = idx & 15;
        short4v t;
#pragma unroll
        for (int j = 0; j < 4; ++j) t[j] = f2b(T[(c4 * 4 + j) * 68 + n]);
        *(short4v*)&Wt[(size_t)(n0 + n) * 256 + k0 + c4 * 4] = t;
    }
}

// ---------------------------------------------------------------------------
// QKV GEMM (r11 measured-best): qkv = x @ Wqkv + b. BM=64, n-super 384
// (grid (256,2)); A staged once; Bs staged; q/k -> qkvb, v -> VtG via Ts.
// ---------------------------------------------------------------------------
__global__ __launch_bounds__(256) void qkv_gemm(
    const float* __restrict__ x, const short* __restrict__ Bt,
    const float* __restrict__ bias, short* __restrict__ qkvb,
    short* __restrict__ VtG)
{
    __shared__ short As[16384];
    __shared__ short Bs[16384];
    __shared__ short Ts[64 * 72];

    const int tid = threadIdx.x;
    const int w = tid >> 6, lane = tid & 63;
    const int l15 = lane & 15, quad = lane >> 4;
    const int m0 = blockIdx.x * 64;
    const int nsup = blockIdx.y * 384;

#pragma unroll
    for (int it = 0; it < 8; ++it) {
        int idx = tid + it * 256;
        int row = ((idx >> 9) << 4) + (idx & 15);
        int col = ((idx >> 6) & 7) * 32 + ((idx >> 4) & 3) * 8;
        const float* src = &x[(size_t)(m0 + row) * 256 + col];
        float4 u = *(const float4*)src, u2 = *(const float4*)(src + 4);
        short8 t;
        t[0] = f2b(u.x);  t[1] = f2b(u.y);  t[2] = f2b(u.z);  t[3] = f2b(u.w);
        t[4] = f2b(u2.x); t[5] = f2b(u2.y); t[6] = f2b(u2.z); t[7] = f2b(u2.w);
        *(short8*)&As[idx * 8] = t;
    }

    for (int t6 = 0; t6 < 6; ++t6) {
        const int n0 = nsup + t6 * 64;
#pragma unroll
        for (int it = 0; it < 8; ++it) {
            int idx = tid + it * 256;
            int n = ((idx >> 9) << 4) + (idx & 15);
            int col = ((idx >> 6) & 7) * 32 + ((idx >> 4) & 3) * 8;
            *(short8*)&Bs[idx * 8] = *(const short8*)&Bt[(size_t)(n0 + n) * 256 + col];
        }
        __syncthreads();

        f32x4 acc[4];
#pragma unroll
        for (int t = 0; t < 4; ++t) acc[t] = (f32x4){0.f, 0.f, 0.f, 0.f};
#pragma unroll
        for (int k0 = 0; k0 < 8; ++k0) {
            short8 a = *(const short8*)&As[((w * 8 + k0) * 64 + lane) * 8];
#pragma unroll
            for (int nt = 0; nt < 4; ++nt) {
                short8 bb = *(const short8*)&Bs[((nt * 8 + k0) * 64 + lane) * 8];
                acc[nt] = MFMA16(a, bb, acc[nt]);
            }
        }

        if (n0 < 512) {
#pragma unroll
            for (int nt = 0; nt < 4; ++nt) {
                int n = n0 + nt * 16 + l15;
                float bv = bias[n];
#pragma unroll
                for (int r = 0; r < 4; ++r)
                    qkvb[(size_t)(m0 + w * 16 + quad * 4 + r) * 768 + n]
                        = f2b(acc[nt][r] + bv);
            }
            __syncthreads();
        } else {
#pragma unroll
            for (int nt = 0; nt < 4; ++nt) {
                int n = n0 + nt * 16 + l15;
                float bv = bias[n];
#pragma unroll
                for (int r = 0; r < 4; ++r)
                    Ts[(nt * 16 + l15) * 72 + w * 16 + quad * 4 + r]
                        = f2b(acc[nt][r] + bv);
            }
            __syncthreads();
            const int d  = tid >> 2;
            const int c  = tid & 3;
            short8 v0 = *(const short8*)&Ts[d * 72 + c * 16];
            short8 v1 = *(const short8*)&Ts[d * 72 + c * 16 + 8];
            const int bg = m0 >> 12, key0 = (m0 & 4095) + c * 16;
            short* dst = &VtG[((size_t)bg * 256 + (n0 - 512) + d) * 4096 + key0];
            *(short8*)dst = v0;
            *(short8*)(dst + 8) = v1;
        }
    }
}

// ---------------------------------------------------------------------------
// Stream-K flash v11: BM=256 (8 waves, 512 thr; 2 waves/SIMD inside ONE
// block — avoids the cross-block co-scheduling refusal of r1/r3), v5's
// verified 3-barrier counted-vmcnt cadence per 32-key unit (instr counts
// scale to 1 K / 2 V per wave -> vmcnt 2/1/0). 256-row tiles halve the
// chip-wide unit count: 4352 = EXACTLY 17 units x 256 CUs. Each block k
// processes global units [17k, 17k+17), flushing o/l per tile crossed
// (<=3 sub-spans). Slot id = k + T_glob (collision-free; per tile the
// contributing sids are contiguous). LDS 48KB; regs 128 VGPR + 128 AGPR.
// ---------------------------------------------------------------------------
__global__ __launch_bounds__(512, 2) void flash_mfma(
    const short* __restrict__ qkv,   // (B*T, 768) bf16 q|k|v
    const short* __restrict__ VtG,   // (B, 256, 4096) bf16 V^T
    short* __restrict__ Opart,       // (NSLOT, 256, 256) bf16
    float* __restrict__ L)           // (NSLOT, 256) fp32
{
    __shared__ short Ks[2][4096];   // 16 keys x 256 dims (8KB each)
    __shared__ short Vs[8192];      // 256 dims x 32 keys (16KB)
    __shared__ short Ps[8192];      // 8 waves x 2 rowsets x 16q x 32 keys (16KB)

    const int tid = threadIdx.x;
    const int w = tid >> 6, lane = tid & 63;   // w = 0..7
    const int l15 = lane & 15, quad = lane >> 4;

    int u_g = blockIdx.x * 17;
    const int u_end = u_g + 17;

    while (u_g < u_end) {
        // ---- decode: global unit -> (batch, 256-row tile, pair offset) ----
        const int b = u_g / 1088;
        const int u_b = u_g - b * 1088;
        int qt = 0;
        while (qt < 15 && u_b >= 4 * (qt + 1) * (qt + 2)) ++qt;
        const int p0 = u_b - 4 * qt * (qt + 1);      // 32-key pair offset
        const int navail = 8 * (qt + 1) - p0;
        const int nrem = u_end - u_g;
        const int npairs = navail < nrem ? navail : nrem;
        const int sid = blockIdx.x + b * 16 + qt;    // partial slot

        const size_t base = (size_t)b * TT * 768;
        const int row0 = qt * 256;
        const int kp_lo = p0;

        // ---- Q frags (A-layout: row=l15, k=quad*8+j) ----
        short8 aq[2][8];
#pragma unroll
        for (int rs = 0; rs < 2; ++rs) {
            const short* qrow = &qkv[base + (size_t)(row0 + rs * 128 + w * 16 + l15) * 768 + quad * 8];
#pragma unroll
            for (int k0 = 0; k0 < 8; ++k0)
                aq[rs][k0] = *(const short8*)&qrow[k0 * 32];
        }

        // ---- prologue: DMA K chunk 0 -> Ks[0] (1 instr/wave) ----
        {
            int idx = tid;
            int row = idx & 15;
            int col = ((idx >> 6) & 7) * 32 + ((idx >> 4) & 3) * 8;
            GL2LDS(&qkv[base + (size_t)(kp_lo * 32 + row) * 768 + 256 + col], &Ks[0][idx * 8]);
        }

        f32x4 o[2][16];
#pragma unroll
        for (int rs = 0; rs < 2; ++rs)
#pragma unroll
            for (int c = 0; c < 16; ++c) o[rs][c] = (f32x4){0.f, 0.f, 0.f, 0.f};
        float l_acc[2][4] = {{0.f, 0.f, 0.f, 0.f}, {0.f, 0.f, 0.f, 0.f}};

        for (int u = 0; u < npairs; ++u) {
            const int j0 = (kp_lo + u) * 32;

            // ===== barrier A: K(2u) ready; all waves past PV(u-1) =====
            __syncthreads();

            // issue K chunk 2u+1 -> Ks[1]  (1 instr/wave, FIRST in queue)
            {
                int idx = tid;
                int row = idx & 15;
                int col = ((idx >> 6) & 7) * 32 + ((idx >> 4) & 3) * 8;
                GL2LDS(&qkv[base + (size_t)(j0 + 16 + row) * 768 + 256 + col], &Ks[1][idx * 8]);
            }
            __builtin_amdgcn_sched_barrier(0);   // pin order: K before V
            // issue V pair u -> Vs (2 instr/wave)
#pragma unroll
            for (int it = 0; it < 2; ++it) {
                int idx = tid + it * 512;
                int d  = ((idx >> 6) << 4) + (idx & 15);
                int kc = ((idx >> 4) & 3) * 8;
                GL2LDS(&VtG[((size_t)b * 256 + d) * 4096 + j0 + kc], &Vs[idx * 8]);
            }
            __builtin_amdgcn_sched_barrier(0);

            // ---- even phase: S = Q K^T on keys [j0, j0+16) ----
            {
                f32x4 s4[2];
                s4[0] = (f32x4){0.f, 0.f, 0.f, 0.f};
                s4[1] = (f32x4){0.f, 0.f, 0.f, 0.f};
#pragma unroll
                for (int k0 = 0; k0 < 8; ++k0) {
                    short8 bb = *(const short8*)&Ks[0][(k0 * 64 + lane) * 8];
                    s4[0] = MFMA16(aq[0][k0], bb, s4[0]);
                    s4[1] = MFMA16(aq[1][k0], bb, s4[1]);
                }
#pragma unroll
                for (int rs = 0; rs < 2; ++rs)
#pragma unroll
                    for (int r = 0; r < 4; ++r) {
                        const int rg = row0 + rs * 128 + w * 16 + quad * 4 + r;
                        int jg = j0 + l15;
                        float xx = s4[rs][r] * 0.0625f;   // 1/sqrt(256)
                        if (jg > rg) xx = -INFINITY;
                        float pv = __expf(fminf(xx, 30.f));
                        l_acc[rs][r] += pv;
                        Ps[((rs * 8 + w) * 64 + (0 * 2 + (l15 >> 3)) * 16 + quad * 4 + r) * 8
                           + (l15 & 7)] = f2b(pv);
                    }
            }

            // ===== barrier B: K(2u+1) done; V(u) in flight =====
            asm volatile("s_waitcnt vmcnt(2)" ::: "memory");
            __builtin_amdgcn_s_barrier();
            __builtin_amdgcn_sched_barrier(0);

            // issue K chunk 2u+2 -> Ks[0] (next pair's even chunk)
            if (u + 1 < npairs) {
                int idx = tid;
                int row = idx & 15;
                int col = ((idx >> 6) & 7) * 32 + ((idx >> 4) & 3) * 8;
                GL2LDS(&qkv[base + (size_t)(j0 + 32 + row) * 768 + 256 + col], &Ks[0][idx * 8]);
            }
            __builtin_amdgcn_sched_barrier(0);

            // ---- odd phase: S = Q K^T on keys [j0+16, j0+32) ----
            {
                f32x4 s4[2];
                s4[0] = (f32x4){0.f, 0.f, 0.f, 0.f};
                s4[1] = (f32x4){0.f, 0.f, 0.f, 0.f};
#pragma unroll
                for (int k0 = 0; k0 < 8; ++k0) {
                    short8 bb = *(const short8*)&Ks[1][(k0 * 64 + lane) * 8];
                    s4[0] = MFMA16(aq[0][k0], bb, s4[0]);
                    s4[1] = MFMA16(aq[1][k0], bb, s4[1]);
                }
#pragma unroll
                for (int rs = 0; rs < 2; ++rs)
#pragma unroll
                    for (int r = 0; r < 4; ++r) {
                        const int rg = row0 + rs * 128 + w * 16 + quad * 4 + r;
                        int jg = j0 + 16 + l15;
                        float xx = s4[rs][r] * 0.0625f;
                        if (jg > rg) xx = -INFINITY;
                        float pv = __expf(fminf(xx, 30.f));
                        l_acc[rs][r] += pv;
                        Ps[((rs * 8 + w) * 64 + (1 * 2 + (l15 >> 3)) * 16 + quad * 4 + r) * 8
                           + (l15 & 7)] = f2b(pv);
                    }
            }

            // ===== barrier C: V(u) landed; K(2u+2) stays in flight =====
            if (u + 1 < npairs) {
                asm volatile("s_waitcnt vmcnt(1)" ::: "memory");
            } else {
                asm volatile("s_waitcnt vmcnt(0)" ::: "memory");
            }
            __builtin_amdgcn_s_barrier();
            __builtin_amdgcn_sched_barrier(0);

            // ---- O += P V over the full 32-key pair ----
            {
                short8 a0 = *(const short8*)&Ps[((0 * 8 + w) * 64 + lane) * 8];
                short8 a1 = *(const short8*)&Ps[((1 * 8 + w) * 64 + lane) * 8];
#pragma unroll
                for (int ct = 0; ct < 16; ++ct) {
                    short8 bb = *(const short8*)&Vs[(ct * 64 + lane) * 8];
                    o[0][ct] = MFMA16(a0, bb, o[0][ct]);
                    o[1][ct] = MFMA16(a1, bb, o[1][ct]);
                }
            }
        }

        // ---- flush partial: reduce l; store bf16 o to slot sid ----
#pragma unroll
        for (int rs = 0; rs < 2; ++rs)
#pragma unroll
            for (int r = 0; r < 4; ++r) {
                float l = l_acc[rs][r];
                l += __shfl_xor(l, 1); l += __shfl_xor(l, 2);
                l += __shfl_xor(l, 4); l += __shfl_xor(l, 8);
                if (l15 == 0)
                    L[(size_t)sid * 256 + rs * 128 + w * 16 + quad * 4 + r] = l;
            }
        const size_t ob = (size_t)sid * (256 * 256);
#pragma unroll
        for (int rs = 0; rs < 2; ++rs)
#pragma unroll
            for (int r = 0; r < 4; ++r) {
                int lr = rs * 128 + w * 16 + quad * 4 + r;
#pragma unroll
                for (int c = 0; c < 16; ++c)
                    Opart[ob + (size_t)lr * 256 + c * 16 + l15] = f2b(o[rs][c][r]);
            }

        u_g += npairs;
    }
}

// ---------------------------------------------------------------------------
// Fused merge + proj GEMM: out = ((sum_s O_s)/l) @ Wproj + b.
// 32-token tiles (grid 512), staged Bs (r10: direct-B regresses), bf16
// Opart. Stream-K decode: tile (b,qt) receives partials from blocks
// k in [S/17, (E-1)/17]; sids contiguous starting at k_first + T_glob.
// nseg <= 9.
// ---------------------------------------------------------------------------
__global__ __launch_bounds__(256) void proj_gemm(
    const short* __restrict__ Opart, const float* __restrict__ L,
    const short* __restrict__ Bt, const float* __restrict__ bias,
    float* __restrict__ out)
{
    __shared__ short As[8192];     // 32 x 256 bf16
    __shared__ short Bs[16384];    // 64 x 256 bf16
    __shared__ float Linv[32];

    const int tid = threadIdx.x;
    const int w = tid >> 6, lane = tid & 63;
    const int l15 = lane & 15, quad = lane >> 4;
    const int t = blockIdx.x;              // 0..511 (32-token tiles)
    const int b = t >> 7, q32 = t & 127;
    const int qt = q32 >> 3;               // 256-row flash tile 0..15
    const int ro = (q32 & 7) * 32;         // row offset inside the flash tile
    const int T_glob = b * 16 + qt;
    const int S = b * 1088 + 4 * qt * (qt + 1);
    const int E = S + 8 * (qt + 1);
    const int k_first = S / 17;
    const int k_last = (E - 1) / 17;
    const int nseg = k_last - k_first + 1; // 1..9
    const int sbase = k_first + T_glob;    // contiguous slot ids
    const int m0 = t * 32;

    if (tid < 32) {
        float l = 0.f;
#pragma unroll
        for (int s2 = 0; s2 < 9; ++s2)
            if (s2 < nseg) l += L[(size_t)(sbase + s2) * 256 + ro + tid];
        Linv[tid] = 1.f / l;
    }
    __syncthreads();

    // ---- stage A = normalized merged bf16 partials -> bf16 ----
#pragma unroll
    for (int it = 0; it < 4; ++it) {
        int idx = tid + it * 256;                       // 0..1023
        int row = ((idx >> 9) << 4) + (idx & 15);       // 0..31
        int col = ((idx >> 6) & 7) * 32 + ((idx >> 4) & 3) * 8;
        float a8[8] = {0.f, 0.f, 0.f, 0.f, 0.f, 0.f, 0.f, 0.f};
#pragma unroll
        for (int s2 = 0; s2 < 9; ++s2) {
            if (s2 < nseg) {
                short8 hv = *(const short8*)&Opart[(size_t)(sbase + s2) * 65536
                                                   + (size_t)(ro + row) * 256 + col];
#pragma unroll
                for (int j = 0; j < 8; ++j) a8[j] += b2f(hv[j]);
            }
        }
        float inv = Linv[row];
        short8 t8;
#pragma unroll
        for (int j = 0; j < 8; ++j) t8[j] = f2b(a8[j] * inv);
        *(short8*)&As[idx * 8] = t8;
    }

    for (int t2 = 0; t2 < 4; ++t2) {
        const int n0 = t2 * 64;
#pragma unroll
        for (int it = 0; it < 8; ++it) {
            int idx = tid + it * 256;                   // 0..2047
            int n = ((idx >> 9) << 4) + (idx & 15);     // 0..63
            int col = ((idx >> 6) & 7) * 32 + ((idx >> 4) & 3) * 8;
            *(short8*)&Bs[idx * 8] = *(const short8*)&Bt[(size_t)(n0 + n) * 256 + col];
        }
        __syncthreads();

        f32x4 acc[2];
        acc[0] = (f32x4){0.f, 0.f, 0.f, 0.f};
        acc[1] = (f32x4){0.f, 0.f, 0.f, 0.f};
#pragma unroll
        for (int k0 = 0; k0 < 8; ++k0) {
            short8 a = *(const short8*)&As[(((w & 1) * 8 + k0) * 64 + lane) * 8];
#pragma unroll
            for (int nt = 0; nt < 2; ++nt) {
                int n16 = (w >> 1) * 2 + nt;
                short8 bb = *(const short8*)&Bs[((n16 * 8 + k0) * 64 + lane) * 8];
                acc[nt] = MFMA16(a, bb, acc[nt]);
            }
        }
#pragma unroll
        for (int nt = 0; nt < 2; ++nt) {
            int n = n0 + ((w >> 1) * 2 + nt) * 16 + l15;
            float bv = bias[n];
#pragma unroll
            for (int r = 0; r < 4; ++r)
                out[(size_t)(m0 + (w & 1) * 16 + quad * 4 + r) * 256 + n] = acc[nt][r] + bv;
        }
        __syncthreads();
    }
}

// ---------------------------------------------------------------------------
extern "C" void kernel_launch(void* const* d_in, const int* in_sizes, int n_in,
                              void* d_out, int out_size, void* d_ws, size_t ws_size,
                              hipStream_t stream)
{
    const float* x     = (const float*)d_in[0];   // (4,4096,256)
    const float* Wqkv  = (const float*)d_in[1];   // (256,768)
    const float* bqkv  = (const float*)d_in[2];   // (768,)
    const float* Wproj = (const float*)d_in[3];   // (256,256)
    const float* bproj = (const float*)d_in[4];   // (256,)
    float* out = (float*)d_out;                   // (4,4096,256) fp32

    const size_t M = (size_t)BB * TT;             // 16384
    short* qkv_b = (short*)d_ws;                  // M x 768 bf16      (25.2 MB)
    short* Wt1   = qkv_b + M * 768;               // 768 x 256 bf16
    short* Wt2   = Wt1 + (size_t)768 * 256;       // 256 x 256 bf16
    short* VtG   = Wt2 + (size_t)256 * 256;       // 4 x 256 x 4096 bf16 (8.4 MB)
    short* Opart = VtG + (size_t)BB * 256 * 4096; // NSLOT x 256 x 256 bf16 (40 MB)
    float* L     = (float*)(Opart + (size_t)NSLOT * 256 * 256); // NSLOT x 256 f32
    // total workspace ~75 MB

    transpose_cast2<<<dim3(4, 16), dim3(256), 0, stream>>>(Wqkv, Wt1, Wproj, Wt2);
    qkv_gemm<<<dim3(256, 2), dim3(256), 0, stream>>>(x, Wt1, bqkv, qkv_b, VtG);
    flash_mfma<<<dim3(256), dim3(512), 0, stream>>>(qkv_b, VtG, Opart, L);
    proj_gemm<<<dim3(512), dim3(256), 0, stream>>>(Opart, L, Wt2, bproj, out);
}